// Round 5
// baseline (506.512 us; speedup 1.0000x reference)
//
#include <hip/hip_runtime.h>

typedef __bf16 bf16x8 __attribute__((ext_vector_type(8)));
typedef float  f32x4  __attribute__((ext_vector_type(4)));
typedef unsigned short u16;
typedef unsigned int   u32;
typedef long long      i64;

#define BSH  7                    // nodes per bucket = 128
#define BCAP 4096                 // max edges per bucket (mean ~2045, 6 sigma safe)

__device__ __forceinline__ float b2f(u16 x){ return __uint_as_float(((u32)x) << 16); }
__device__ __forceinline__ u16 f2b(float x){
  u32 u = __float_as_uint(x);
  return (u16)((u + 0x7FFFu + ((u >> 16) & 1u)) >> 16);
}

// flags[0] = 1 if float tensors are f32 on device (else bf16)
// flags[1] = 1 if edge_index is int64 on device (else int32)
__global__ __launch_bounds__(256) void k_detect(const u16* __restrict__ x,
                                                const u32* __restrict__ ei,
                                                int* __restrict__ flags){
  __shared__ int sh[2];
  int t = threadIdx.x;
  if (t < 2) sh[t] = 0;
  __syncthreads();
  int sane = 0;
  for (int i = t; i < 4096; i += 256){
    u16 u = x[i]; u32 e = (u >> 7) & 0xFFu;
    if (u == 0 || (e >= 0x70u && e <= 0x8Fu)) sane++;
  }
  int nz = 0;
  for (int i = t; i < 1024; i += 256)
    if (ei[2*i + 1] != 0u) nz++;
  atomicAdd(&sh[0], sane);
  atomicAdd(&sh[1], nz);
  __syncthreads();
  if (t == 0){
    flags[0] = (sh[0] < 3500) ? 1 : 0;
    flags[1] = (sh[1] == 0) ? 1 : 0;
  }
}

__device__ __forceinline__ int ld_idx(const void* ei, long long j, int is64){
  return is64 ? (int)((const i64*)ei)[j] : ((const int*)ei)[j];
}
__device__ __forceinline__ float ld_f(const void* p, int j, int isf32){
  return isf32 ? ((const float*)p)[j] : b2f(((const u16*)p)[j]);
}

__global__ void k_zerob(int* __restrict__ bcnt, int nbuk){
  int i = blockIdx.x*blockDim.x + threadIdx.x;
  if (i < nbuk) bcnt[i] = 0;
}

// phase 1: scatter edges into dst-range buckets (packed src | ldst<<17)
__global__ void k_bucket(const void* __restrict__ ei, int E, int n,
                         int* __restrict__ bcnt, u32* __restrict__ ebuf,
                         const int* __restrict__ flags){
  int e = blockIdx.x*blockDim.x + threadIdx.x;
  if (e >= E) return;
  int is64 = flags[1];
  int d = ld_idx(ei, (long long)E + e, is64);
  int s = ld_idx(ei, e, is64);
  if ((unsigned)d < (unsigned)n && (unsigned)s < (unsigned)n){
    int b = d >> BSH;
    int p = atomicAdd(&bcnt[b], 1);
    if (p < BCAP) ebuf[(size_t)b*BCAP + p] = (u32)s | ((u32)(d & ((1<<BSH)-1)) << 17);
  }
}

// phase 1.5: per-bucket LDS histogram -> deg (replaces global-atomic k_deg)
__global__ __launch_bounds__(256) void k_bdeg(const int* __restrict__ bcnt,
                                              const u32* __restrict__ ebuf,
                                              int* __restrict__ deg, int n){
  __shared__ int cnt[1<<BSH];
  int b = blockIdx.x, t = threadIdx.x;
  if (t < (1<<BSH)) cnt[t] = 0;
  __syncthreads();
  int m = bcnt[b]; if (m > BCAP) m = BCAP;
  const u32* eb = ebuf + (size_t)b*BCAP;
  for (int i = t; i < m; i += 256)
    atomicAdd(&cnt[eb[i] >> 17], 1);
  __syncthreads();
  if (t < (1<<BSH)){
    int node = (b << BSH) + t;
    if (node < n) deg[node] = cnt[t];
  }
}

// ---- hierarchical scan ----
__global__ __launch_bounds__(256) void k_scanA(const int* __restrict__ deg, int n,
                                               int* __restrict__ bsum){
  __shared__ int sh[256];
  int t = threadIdx.x;
  int base = blockIdx.x*1024 + t*4;
  int s = 0;
  #pragma unroll
  for (int i = 0; i < 4; ++i){ int idx = base + i; if (idx < n) s += deg[idx]; }
  sh[t] = s; __syncthreads();
  for (int off = 128; off; off >>= 1){
    if (t < off) sh[t] += sh[t + off];
    __syncthreads();
  }
  if (t == 0) bsum[blockIdx.x] = sh[0];
}

__global__ __launch_bounds__(256) void k_scanB(int* __restrict__ bsum, int nB,
                                               int* __restrict__ rowptr, int n){
  __shared__ int sh[256];
  int t = threadIdx.x;
  int v = (t < nB) ? bsum[t] : 0;
  sh[t] = v; __syncthreads();
  for (int off = 1; off < 256; off <<= 1){
    int u = 0; if (t >= off) u = sh[t - off];
    __syncthreads(); sh[t] += u; __syncthreads();
  }
  if (t < nB) bsum[t] = sh[t] - v;
  if (t == 255) rowptr[n] = sh[255];
}

__global__ __launch_bounds__(256) void k_scanC(const int* __restrict__ deg, int n,
                                               const int* __restrict__ bsum,
                                               int* __restrict__ rowptr,
                                               float* __restrict__ dis){
  __shared__ int sh[256];
  int t = threadIdx.x;
  int base = blockIdx.x*1024 + t*4;
  int d[4]; int s = 0;
  #pragma unroll
  for (int i = 0; i < 4; ++i){ int idx = base + i; d[i] = (idx < n) ? deg[idx] : 0; s += d[i]; }
  sh[t] = s; __syncthreads();
  for (int off = 1; off < 256; off <<= 1){
    int u = 0; if (t >= off) u = sh[t - off];
    __syncthreads(); sh[t] += u; __syncthreads();
  }
  int run = bsum[blockIdx.x] + sh[t] - s;
  #pragma unroll
  for (int i = 0; i < 4; ++i){
    int idx = base + i;
    if (idx < n){
      rowptr[idx] = run; run += d[i];
      dis[idx] = rsqrtf((float)(d[i] + 1));
    }
  }
}

// phase 2: per-bucket CSR fill with LDS cursors (colx window is L2-local)
__global__ __launch_bounds__(256) void k_bfill(const int* __restrict__ bcnt,
                                               const u32* __restrict__ ebuf,
                                               const int* __restrict__ rowptr,
                                               int* __restrict__ colx, int n){
  __shared__ int cur[1<<BSH];
  int b = blockIdx.x, t = threadIdx.x;
  if (t < (1<<BSH)){
    int node = (b << BSH) + t;
    cur[t] = (node < n) ? rowptr[node] : 0;
  }
  __syncthreads();
  int m = bcnt[b]; if (m > BCAP) m = BCAP;
  const u32* eb = ebuf + (size_t)b*BCAP;
  for (int i = t; i < m; i += 256){
    u32 e = eb[i];
    int p = atomicAdd(&cur[e >> 17], 1);
    colx[p] = (int)(e & 0x1FFFFu);
  }
}

// pre-shuffle W (128x128) into MFMA B-fragment order (bf16 out)
__global__ __launch_bounds__(64) void k_shufW(const void* __restrict__ W, u16* __restrict__ Ws,
                                              const int* __restrict__ flags){
  int f = flags[0];
  int bid = blockIdx.x;          // 0..31
  int nt = bid >> 2, kk = bid & 3;
  int l = threadIdx.x;
  int g = l >> 4, mr = l & 15;
  int nn = nt*16 + mr;
  #pragma unroll
  for (int i = 0; i < 8; ++i){
    int k = kk*32 + g*4 + (i & 3) + ((i >> 2) << 4);
    u16 w = f ? f2b(((const float*)W)[k*128 + nn]) : ((const u16*)W)[k*128 + nn];
    Ws[(size_t)(bid*64 + l)*8 + i] = w;
  }
}

// T = (A @ W) * dis[row], bf16 out. One wave per 16-row tile.
__global__ __launch_bounds__(256) void k_gemm(const void* __restrict__ A, int aExt,
    const u16* __restrict__ Ws, const float* __restrict__ dis,
    u16* __restrict__ T, int nTiles, const int* __restrict__ flags)
{
  int wave = threadIdx.x >> 6, lane = threadIdx.x & 63;
  int tile = blockIdx.x*4 + wave;
  if (tile >= nTiles) return;
  int g = lane >> 4, mr = lane & 15;
  int f = aExt ? flags[0] : 0;
  union U8 { ushort4 q[2]; u16 s[8]; bf16x8 b; };
  bf16x8 a[4];
  if (f){
    const float* ap = (const float*)A + (size_t)(tile*16 + mr)*128;
    #pragma unroll
    for (int kk = 0; kk < 4; ++kk){
      float4 p = *(const float4*)(ap + kk*32 + g*4);
      float4 q = *(const float4*)(ap + kk*32 + g*4 + 16);
      U8 u;
      u.s[0]=f2b(p.x); u.s[1]=f2b(p.y); u.s[2]=f2b(p.z); u.s[3]=f2b(p.w);
      u.s[4]=f2b(q.x); u.s[5]=f2b(q.y); u.s[6]=f2b(q.z); u.s[7]=f2b(q.w);
      a[kk] = u.b;
    }
  } else {
    const u16* ap = (const u16*)A + (size_t)(tile*16 + mr)*128;
    #pragma unroll
    for (int kk = 0; kk < 4; ++kk){
      U8 u;
      u.q[0] = *(const ushort4*)(ap + kk*32 + g*4);
      u.q[1] = *(const ushort4*)(ap + kk*32 + g*4 + 16);
      a[kk] = u.b;
    }
  }
  float dj[4];
  #pragma unroll
  for (int j = 0; j < 4; ++j) dj[j] = dis[tile*16 + g*4 + j];
  #pragma unroll
  for (int nt = 0; nt < 8; ++nt){
    f32x4 acc = {0.f,0.f,0.f,0.f};
    #pragma unroll
    for (int kk = 0; kk < 4; ++kk){
      bf16x8 b = *(const bf16x8*)(Ws + (size_t)((nt*4 + kk)*64 + lane)*8);
      acc = __builtin_amdgcn_mfma_f32_16x16x32_bf16(a[kk], b, acc, 0, 0, 0);
    }
    int nn = nt*16 + mr;
    #pragma unroll
    for (int j = 0; j < 4; ++j){
      int row = tile*16 + g*4 + j;
      T[(size_t)row*128 + nn] = f2b(acc[j] * dj[j]);
    }
  }
}

// aggregation + bias + epilogue. One wave per node, 4 nodes per block.
template<int MODE>
__global__ __launch_bounds__(256) void k_agg(const u16* __restrict__ T,
    const int* __restrict__ rowptr, const int* __restrict__ colx,
    const float* __restrict__ dis, const void* __restrict__ bias,
    const void* __restrict__ lg, const void* __restrict__ lb,
    void* __restrict__ outA, int n, const int* __restrict__ flags)
{
  int wave = threadIdx.x >> 6, l = threadIdx.x & 63;
  int v = blockIdx.x*4 + wave; if (v >= n) return;
  int f = flags[0];
  int d0 = l*2;
  u32 self = *(const u32*)(T + (size_t)v*128 + d0);
  float p0 = b2f((u16)(self & 0xffff)), p1 = b2f((u16)(self >> 16));
  float q0 = 0.f, q1 = 0.f, r0 = 0.f, r1 = 0.f, t0 = 0.f, t1 = 0.f;
  int s = rowptr[v], e = rowptr[v+1];
  for (int base = s; base < e; base += 64){
    int cnt = e - base; if (cnt > 64) cnt = 64;
    int my = (base + l < e) ? colx[base + l] : 0;
    int i = 0;
    for (; i + 4 <= cnt; i += 4){
      int nb0 = __shfl(my, i), nb1 = __shfl(my, i+1);
      int nb2 = __shfl(my, i+2), nb3 = __shfl(my, i+3);
      u32 u0 = *(const u32*)(T + (size_t)nb0*128 + d0);
      u32 u1 = *(const u32*)(T + (size_t)nb1*128 + d0);
      u32 u2 = *(const u32*)(T + (size_t)nb2*128 + d0);
      u32 u3 = *(const u32*)(T + (size_t)nb3*128 + d0);
      p0 += b2f((u16)(u0 & 0xffff)); p1 += b2f((u16)(u0 >> 16));
      q0 += b2f((u16)(u1 & 0xffff)); q1 += b2f((u16)(u1 >> 16));
      r0 += b2f((u16)(u2 & 0xffff)); r1 += b2f((u16)(u2 >> 16));
      t0 += b2f((u16)(u3 & 0xffff)); t1 += b2f((u16)(u3 >> 16));
    }
    for (; i < cnt; ++i){
      int nb = __shfl(my, i);
      u32 u = *(const u32*)(T + (size_t)nb*128 + d0);
      p0 += b2f((u16)(u & 0xffff)); p1 += b2f((u16)(u >> 16));
    }
  }
  float a0 = (p0 + q0) + (r0 + t0);
  float a1 = (p1 + q1) + (r1 + t1);
  float sc = dis[v];
  float x0 = fmaf(a0, sc, ld_f(bias, d0,   f));
  float x1 = fmaf(a1, sc, ld_f(bias, d0+1, f));
  if (MODE == 0){
    x0 = fmaxf(x0, 0.f); x1 = fmaxf(x1, 0.f);
    float sum = x0 + x1;
    #pragma unroll
    for (int off = 32; off; off >>= 1) sum += __shfl_xor(sum, off);
    float mu = sum * (1.f/128.f);
    float e0 = x0 - mu, e1 = x1 - mu;
    float vs = e0*e0 + e1*e1;
    #pragma unroll
    for (int off = 32; off; off >>= 1) vs += __shfl_xor(vs, off);
    float inv = rsqrtf(vs*(1.f/128.f) + 1e-5f);
    u16* oa = (u16*)outA;
    oa[(size_t)v*128 + d0]   = f2b(e0*inv*ld_f(lg, d0,   f) + ld_f(lb, d0,   f));
    oa[(size_t)v*128 + d0+1] = f2b(e1*inv*ld_f(lg, d0+1, f) + ld_f(lb, d0+1, f));
  } else {
    if (f){
      float* oa = (float*)outA;
      oa[(size_t)v*128 + d0]   = x0;
      oa[(size_t)v*128 + d0+1] = x1;
    } else {
      u16* oa = (u16*)outA;
      oa[(size_t)v*128 + d0]   = f2b(x0);
      oa[(size_t)v*128 + d0+1] = f2b(x1);
    }
  }
}

// collapse post_mp: Wc = mpW1 @ mpW2 (128x40 f32), bc = mpb1 @ mpW2 + mpb2
// flag hoisted, tight unrolled loops (round-4 version was branch-serialized)
__global__ __launch_bounds__(128) void k_wc(const void* __restrict__ mpW1, const void* __restrict__ mpb1,
    const void* __restrict__ mpW2, const void* __restrict__ mpb2,
    float* __restrict__ Wc, float* __restrict__ bc, const int* __restrict__ flags)
{
  int f = flags[0];
  int c = blockIdx.x;   // 0..39
  int k = threadIdx.x;  // 0..127
  float acc = 0.f;
  if (f){
    const float* A  = (const float*)mpW1 + (size_t)k*128;
    const float* B2 = (const float*)mpW2;
    #pragma unroll 8
    for (int j = 0; j < 128; ++j) acc = fmaf(A[j], B2[j*40 + c], acc);
    if (k == 0){
      const float* b1p = (const float*)mpb1;
      float b = ((const float*)mpb2)[c];
      #pragma unroll 8
      for (int j = 0; j < 128; ++j) b = fmaf(b1p[j], B2[j*40 + c], b);
      bc[c] = b;
    }
  } else {
    const u16* A  = (const u16*)mpW1 + (size_t)k*128;
    const u16* B2 = (const u16*)mpW2;
    #pragma unroll 8
    for (int j = 0; j < 128; ++j) acc = fmaf(b2f(A[j]), b2f(B2[j*40 + c]), acc);
    if (k == 0){
      const u16* b1p = (const u16*)mpb1;
      float b = b2f(((const u16*)mpb2)[c]);
      #pragma unroll 8
      for (int j = 0; j < 128; ++j) b = fmaf(b2f(b1p[j]), b2f(B2[j*40 + c]), b);
      bc[c] = b;
    }
  }
  Wc[k*40 + c] = acc;
}

// shuffle Wc (128x40 f32) -> bf16 B-frags padded to 48 cols. 12 frags.
__global__ __launch_bounds__(64) void k_shufWc(const float* __restrict__ Wc, u16* __restrict__ Wcs){
  int bid = blockIdx.x;          // 0..11
  int nt = bid >> 2, kk = bid & 3;
  int l = threadIdx.x;
  int g = l >> 4, mr = l & 15;
  int nn = nt*16 + mr;
  #pragma unroll
  for (int i = 0; i < 8; ++i){
    int k = kk*32 + g*4 + (i & 3) + ((i >> 2) << 4);
    Wcs[(size_t)(bid*64 + l)*8 + i] = (nn < 40) ? f2b(Wc[k*40 + nn]) : (u16)0;
  }
}

// logits via MFMA + in-register log_softmax. One wave per 16-node tile.
__global__ __launch_bounds__(256) void k_logitsM(const u16* __restrict__ Wcs,
    const float* __restrict__ bc, void* __restrict__ dout, int n,
    const int* __restrict__ flags)
{
  int wave = threadIdx.x >> 6, lane = threadIdx.x & 63;
  int tile = blockIdx.x*4 + wave;
  int nTiles = n >> 4;
  if (tile >= nTiles) return;
  int f = flags[0];
  int g = lane >> 4, mr = lane & 15;
  union U8 { ushort4 q[2]; u16 s[8]; bf16x8 b; };
  bf16x8 a[4];
  if (f){
    const float* ap = (const float*)dout + (size_t)(tile*16 + mr)*128;
    #pragma unroll
    for (int kk = 0; kk < 4; ++kk){
      float4 p = *(const float4*)(ap + kk*32 + g*4);
      float4 q = *(const float4*)(ap + kk*32 + g*4 + 16);
      U8 u;
      u.s[0]=f2b(fmaxf(p.x,0.f)); u.s[1]=f2b(fmaxf(p.y,0.f));
      u.s[2]=f2b(fmaxf(p.z,0.f)); u.s[3]=f2b(fmaxf(p.w,0.f));
      u.s[4]=f2b(fmaxf(q.x,0.f)); u.s[5]=f2b(fmaxf(q.y,0.f));
      u.s[6]=f2b(fmaxf(q.z,0.f)); u.s[7]=f2b(fmaxf(q.w,0.f));
      a[kk] = u.b;
    }
  } else {
    const u16* ap = (const u16*)dout + (size_t)(tile*16 + mr)*128;
    #pragma unroll
    for (int kk = 0; kk < 4; ++kk){
      U8 u;
      u.q[0] = *(const ushort4*)(ap + kk*32 + g*4);
      u.q[1] = *(const ushort4*)(ap + kk*32 + g*4 + 16);
      #pragma unroll
      for (int i = 0; i < 8; ++i) u.s[i] = (u.s[i] & 0x8000u) ? (u16)0 : u.s[i];  // relu
      a[kk] = u.b;
    }
  }
  f32x4 acc[3];
  #pragma unroll
  for (int nt = 0; nt < 3; ++nt){
    f32x4 c4 = {0.f,0.f,0.f,0.f};
    #pragma unroll
    for (int kk = 0; kk < 4; ++kk){
      bf16x8 b = *(const bf16x8*)(Wcs + (size_t)((nt*4 + kk)*64 + lane)*8);
      c4 = __builtin_amdgcn_mfma_f32_16x16x32_bf16(a[kk], b, c4, 0, 0, 0);
    }
    acc[nt] = c4;
  }
  float bcv[3]; bool valid[3];
  #pragma unroll
  for (int nt = 0; nt < 3; ++nt){
    int c = nt*16 + mr;
    valid[nt] = (c < 40);
    bcv[nt] = valid[nt] ? bc[c] : 0.f;
  }
  float* of = (float*)dout + (size_t)n*128;
  u16*  ob = (u16*) dout + (size_t)n*128;
  #pragma unroll
  for (int j = 0; j < 4; ++j){
    float l0 = valid[0] ? acc[0][j] + bcv[0] : -3.0e38f;
    float l1 = valid[1] ? acc[1][j] + bcv[1] : -3.0e38f;
    float l2 = valid[2] ? acc[2][j] + bcv[2] : -3.0e38f;
    float m = fmaxf(l0, fmaxf(l1, l2));
    #pragma unroll
    for (int off = 8; off; off >>= 1) m = fmaxf(m, __shfl_xor(m, off));
    float ssum = (valid[0] ? expf(l0 - m) : 0.f)
               + (valid[1] ? expf(l1 - m) : 0.f)
               + (valid[2] ? expf(l2 - m) : 0.f);
    #pragma unroll
    for (int off = 8; off; off >>= 1) ssum += __shfl_xor(ssum, off);
    float lgs = m + logf(ssum);
    int node = tile*16 + g*4 + j;
    #pragma unroll
    for (int nt = 0; nt < 3; ++nt){
      if (valid[nt]){
        int c = nt*16 + mr;
        float r = (nt==0 ? l0 : (nt==1 ? l1 : l2)) - lgs;
        if (f) of[(size_t)node*40 + c] = r;
        else   ob[(size_t)node*40 + c] = f2b(r);
      }
    }
  }
}

extern "C" void kernel_launch(void* const* d_in, const int* in_sizes, int n_in,
                              void* d_out, int out_size, void* d_ws, size_t ws_size,
                              hipStream_t stream)
{
  const int n = in_sizes[0] / 128;
  const int E = in_sizes[1] / 2;

  const void* x    = d_in[0];
  const void* ei   = d_in[1];
  const void* W1   = d_in[2];
  const void* b1   = d_in[3];
  const void* W2   = d_in[4];
  const void* b2   = d_in[5];
  const void* W3   = d_in[6];
  const void* b3   = d_in[7];
  const void* ln1g = d_in[8];
  const void* ln1b = d_in[9];
  const void* ln2g = d_in[10];
  const void* ln2b = d_in[11];
  const void* mpW1 = d_in[12];
  const void* mpb1 = d_in[13];
  const void* mpW2 = d_in[14];
  const void* mpb2 = d_in[15];

  u16* Hbuf = (u16*)d_out;  // d_out emb region doubles as H buffer until layer 3

  char* w = (char*)d_ws;
  size_t off = 0;
  auto alloc = [&](size_t bytes)->char*{
    char* p = w + off; off = (off + bytes + 255) & ~(size_t)255; return p;
  };
  const int nbuk = (n + (1<<BSH) - 1) >> BSH;

  int*   flags = (int*)  alloc(256);
  float* dis   = (float*)alloc((size_t)n*4);
  int*   deg   = (int*)  alloc((size_t)n*4);
  int*   rowp  = (int*)  alloc((size_t)(n+1)*4);
  int*   bsum  = (int*)  alloc(1024);
  int*   bcnt  = (int*)  alloc((size_t)nbuk*4);
  u32*   ebuf  = (u32*)  alloc((size_t)nbuk*BCAP*4);
  int*   colx  = (int*)  alloc((size_t)E*4 + 256);
  u16*   T     = (u16*)  alloc((size_t)n*128*2);
  u16*   Ws    = (u16*)  alloc((size_t)128*128*2);
  float* Wc    = (float*)alloc((size_t)128*40*4);
  float* bc    = (float*)alloc((size_t)64*4);
  u16*   Wcs   = (u16*)  alloc((size_t)12*64*8*2);

  int gE = (E + 255) / 256;
  int nB = (n + 1023) / 1024;

  k_detect<<<1, 256, 0, stream>>>((const u16*)x, (const u32*)ei, flags);
  k_zerob <<<(nbuk + 255)/256, 256, 0, stream>>>(bcnt, nbuk);
  k_bucket<<<gE, 256, 0, stream>>>(ei, E, n, bcnt, ebuf, flags);
  k_bdeg  <<<nbuk, 256, 0, stream>>>(bcnt, ebuf, deg, n);
  k_scanA <<<nB, 256, 0, stream>>>(deg, n, bsum);
  k_scanB <<<1, 256, 0, stream>>>(bsum, nB, rowp, n);
  k_scanC <<<nB, 256, 0, stream>>>(deg, n, bsum, rowp, dis);
  k_bfill <<<nbuk, 256, 0, stream>>>(bcnt, ebuf, rowp, colx, n);
  k_wc    <<<40, 128, 0, stream>>>(mpW1, mpb1, mpW2, mpb2, Wc, bc, flags);
  k_shufWc<<<12, 64, 0, stream>>>(Wc, Wcs);

  int nTiles = (n + 15) / 16;
  int gG = (nTiles + 3) / 4;
  int gA = (n + 3) / 4;

  // layer 0
  k_shufW<<<32, 64, 0, stream>>>(W1, Ws, flags);
  k_gemm <<<gG, 256, 0, stream>>>(x, 1, Ws, dis, T, nTiles, flags);
  k_agg<0><<<gA, 256, 0, stream>>>(T, rowp, colx, dis, b1, ln1g, ln1b, Hbuf, n, flags);
  // layer 1
  k_shufW<<<32, 64, 0, stream>>>(W2, Ws, flags);
  k_gemm <<<gG, 256, 0, stream>>>(Hbuf, 0, Ws, dis, T, nTiles, flags);
  k_agg<0><<<gA, 256, 0, stream>>>(T, rowp, colx, dis, b2, ln2g, ln2b, Hbuf, n, flags);
  // layer 2: emb -> d_out
  k_shufW<<<32, 64, 0, stream>>>(W3, Ws, flags);
  k_gemm <<<gG, 256, 0, stream>>>(Hbuf, 0, Ws, dis, T, nTiles, flags);
  k_agg<1><<<gA, 256, 0, stream>>>(T, rowp, colx, dis, b3, nullptr, nullptr, d_out, n, flags);
  // post_mp collapsed + log_softmax (MFMA)
  k_logitsM<<<gG, 256, 0, stream>>>(Wcs, bc, d_out, n, flags);
}

// Round 6
// 263.689 us; speedup vs baseline: 1.9209x; 1.9209x over previous
//
#include <hip/hip_runtime.h>

typedef __bf16 bf16x8 __attribute__((ext_vector_type(8)));
typedef float  f32x4  __attribute__((ext_vector_type(4)));
typedef unsigned short u16;
typedef unsigned int   u32;
typedef long long      i64;

#define BSH  7                    // nodes per bucket = 128
#define BCAP 4096                 // max edges per bucket (mean ~2045)
#define NPB  64                   // partition blocks

__device__ __forceinline__ float b2f(u16 x){ return __uint_as_float(((u32)x) << 16); }
__device__ __forceinline__ u16 f2b(float x){
  u32 u = __float_as_uint(x);
  return (u16)((u + 0x7FFFu + ((u >> 16) & 1u)) >> 16);
}

// flags[0] = 1 if float tensors are f32 on device (else bf16)
// flags[1] = 1 if edge_index is int64 on device (else int32)
__global__ __launch_bounds__(256) void k_detect(const u16* __restrict__ x,
                                                const u32* __restrict__ ei,
                                                int* __restrict__ flags){
  __shared__ int sh[2];
  int t = threadIdx.x;
  if (t < 2) sh[t] = 0;
  __syncthreads();
  int sane = 0;
  for (int i = t; i < 4096; i += 256){
    u16 u = x[i]; u32 e = (u >> 7) & 0xFFu;
    if (u == 0 || (e >= 0x70u && e <= 0x8Fu)) sane++;
  }
  int nz = 0;
  for (int i = t; i < 1024; i += 256)
    if (ei[2*i + 1] != 0u) nz++;
  atomicAdd(&sh[0], sane);
  atomicAdd(&sh[1], nz);
  __syncthreads();
  if (t == 0){
    flags[0] = (sh[0] < 3500) ? 1 : 0;
    flags[1] = (sh[1] == 0) ? 1 : 0;
  }
}

__device__ __forceinline__ int ld_idx(const void* ei, long long j, int is64){
  return is64 ? (int)((const i64*)ei)[j] : ((const int*)ei)[j];
}
__device__ __forceinline__ float ld_f(const void* p, int j, int isf32){
  return isf32 ? ((const float*)p)[j] : b2f(((const u16*)p)[j]);
}

__global__ void k_zerob(int* __restrict__ bcnt, int nbuk){
  int i = blockIdx.x*blockDim.x + threadIdx.x;
  if (i < nbuk) bcnt[i] = 0;
}

// LDS-aggregated partition: each block owns a contiguous edge range.
// A) LDS histogram  B) one global atomicAdd per (block,bucket) to reserve
// C) re-read edges, scatter via LDS cursors into reserved ranges.
__global__ __launch_bounds__(256) void k_part(const void* __restrict__ ei, int E, int n,
                                              int* __restrict__ bcnt, u32* __restrict__ ebuf,
                                              const int* __restrict__ flags, int nbuk){
  __shared__ int cnt[512], base[512], cur[512];
  int t = threadIdx.x;
  int is64 = flags[1];
  for (int i = t; i < 512; i += 256){ cnt[i] = 0; cur[i] = 0; }
  __syncthreads();
  long long R = ((long long)E + NPB - 1) / NPB;
  long long lo = (long long)blockIdx.x * R;
  long long hi = lo + R; if (hi > E) hi = E;
  // phase A: histogram
  for (long long e = lo + t; e < hi; e += 256){
    int d = ld_idx(ei, (long long)E + e, is64);
    int s = ld_idx(ei, e, is64);
    if ((unsigned)d < (unsigned)n && (unsigned)s < (unsigned)n){
      int b = d >> BSH;
      if (b < 512) atomicAdd(&cnt[b], 1);
    }
  }
  __syncthreads();
  // phase B: reserve global ranges (one atomic per nonempty bucket)
  for (int b = t; b < 512; b += 256){
    int c = cnt[b];
    base[b] = (b < nbuk && c > 0) ? atomicAdd(&bcnt[b], c) : 0;
  }
  __syncthreads();
  // phase C: scatter (packed: src | local_dst << 17)
  for (long long e = lo + t; e < hi; e += 256){
    int d = ld_idx(ei, (long long)E + e, is64);
    int s = ld_idx(ei, e, is64);
    if ((unsigned)d < (unsigned)n && (unsigned)s < (unsigned)n){
      int b = d >> BSH;
      if (b < 512){
        int p = base[b] + atomicAdd(&cur[b], 1);
        if (p < BCAP) ebuf[(size_t)b*BCAP + p] = (u32)s | ((u32)(d & ((1<<BSH)-1)) << 17);
      }
    }
  }
}

// per-bucket LDS histogram -> deg
__global__ __launch_bounds__(256) void k_bdeg(const int* __restrict__ bcnt,
                                              const u32* __restrict__ ebuf,
                                              int* __restrict__ deg, int n){
  __shared__ int cnt[1<<BSH];
  int b = blockIdx.x, t = threadIdx.x;
  if (t < (1<<BSH)) cnt[t] = 0;
  __syncthreads();
  int m = bcnt[b]; if (m > BCAP) m = BCAP;
  const u32* eb = ebuf + (size_t)b*BCAP;
  for (int i = t; i < m; i += 256)
    atomicAdd(&cnt[eb[i] >> 17], 1);
  __syncthreads();
  if (t < (1<<BSH)){
    int node = (b << BSH) + t;
    if (node < n) deg[node] = cnt[t];
  }
}

// ---- hierarchical scan ----
__global__ __launch_bounds__(256) void k_scanA(const int* __restrict__ deg, int n,
                                               int* __restrict__ bsum){
  __shared__ int sh[256];
  int t = threadIdx.x;
  int base = blockIdx.x*1024 + t*4;
  int s = 0;
  #pragma unroll
  for (int i = 0; i < 4; ++i){ int idx = base + i; if (idx < n) s += deg[idx]; }
  sh[t] = s; __syncthreads();
  for (int off = 128; off; off >>= 1){
    if (t < off) sh[t] += sh[t + off];
    __syncthreads();
  }
  if (t == 0) bsum[blockIdx.x] = sh[0];
}

__global__ __launch_bounds__(256) void k_scanB(int* __restrict__ bsum, int nB,
                                               int* __restrict__ rowptr, int n){
  __shared__ int sh[256];
  int t = threadIdx.x;
  int v = (t < nB) ? bsum[t] : 0;
  sh[t] = v; __syncthreads();
  for (int off = 1; off < 256; off <<= 1){
    int u = 0; if (t >= off) u = sh[t - off];
    __syncthreads(); sh[t] += u; __syncthreads();
  }
  if (t < nB) bsum[t] = sh[t] - v;
  if (t == 255) rowptr[n] = sh[255];
}

__global__ __launch_bounds__(256) void k_scanC(const int* __restrict__ deg, int n,
                                               const int* __restrict__ bsum,
                                               int* __restrict__ rowptr,
                                               float* __restrict__ dis){
  __shared__ int sh[256];
  int t = threadIdx.x;
  int base = blockIdx.x*1024 + t*4;
  int d[4]; int s = 0;
  #pragma unroll
  for (int i = 0; i < 4; ++i){ int idx = base + i; d[i] = (idx < n) ? deg[idx] : 0; s += d[i]; }
  sh[t] = s; __syncthreads();
  for (int off = 1; off < 256; off <<= 1){
    int u = 0; if (t >= off) u = sh[t - off];
    __syncthreads(); sh[t] += u; __syncthreads();
  }
  int run = bsum[blockIdx.x] + sh[t] - s;
  #pragma unroll
  for (int i = 0; i < 4; ++i){
    int idx = base + i;
    if (idx < n){
      rowptr[idx] = run; run += d[i];
      dis[idx] = rsqrtf((float)(d[i] + 1));
    }
  }
}

// per-bucket CSR fill with LDS cursors (colx window is L2-local)
__global__ __launch_bounds__(256) void k_bfill(const int* __restrict__ bcnt,
                                               const u32* __restrict__ ebuf,
                                               const int* __restrict__ rowptr,
                                               int* __restrict__ colx, int n){
  __shared__ int cur[1<<BSH];
  int b = blockIdx.x, t = threadIdx.x;
  if (t < (1<<BSH)){
    int node = (b << BSH) + t;
    cur[t] = (node < n) ? rowptr[node] : 0;
  }
  __syncthreads();
  int m = bcnt[b]; if (m > BCAP) m = BCAP;
  const u32* eb = ebuf + (size_t)b*BCAP;
  for (int i = t; i < m; i += 256){
    u32 e = eb[i];
    int p = atomicAdd(&cur[e >> 17], 1);
    colx[p] = (int)(e & 0x1FFFFu);
  }
}

// pre-shuffle W (128x128) into MFMA B-fragment order (bf16 out)
__global__ __launch_bounds__(64) void k_shufW(const void* __restrict__ W, u16* __restrict__ Ws,
                                              const int* __restrict__ flags){
  int f = flags[0];
  int bid = blockIdx.x;          // 0..31
  int nt = bid >> 2, kk = bid & 3;
  int l = threadIdx.x;
  int g = l >> 4, mr = l & 15;
  int nn = nt*16 + mr;
  #pragma unroll
  for (int i = 0; i < 8; ++i){
    int k = kk*32 + g*4 + (i & 3) + ((i >> 2) << 4);
    u16 w = f ? f2b(((const float*)W)[k*128 + nn]) : ((const u16*)W)[k*128 + nn];
    Ws[(size_t)(bid*64 + l)*8 + i] = w;
  }
}

// T = (A @ W) * dis[row], bf16 out. One wave per 16-row tile.
__global__ __launch_bounds__(256) void k_gemm(const void* __restrict__ A, int aExt,
    const u16* __restrict__ Ws, const float* __restrict__ dis,
    u16* __restrict__ T, int nTiles, const int* __restrict__ flags)
{
  int wave = threadIdx.x >> 6, lane = threadIdx.x & 63;
  int tile = blockIdx.x*4 + wave;
  if (tile >= nTiles) return;
  int g = lane >> 4, mr = lane & 15;
  int f = aExt ? flags[0] : 0;
  union U8 { ushort4 q[2]; u16 s[8]; bf16x8 b; };
  bf16x8 a[4];
  if (f){
    const float* ap = (const float*)A + (size_t)(tile*16 + mr)*128;
    #pragma unroll
    for (int kk = 0; kk < 4; ++kk){
      float4 p = *(const float4*)(ap + kk*32 + g*4);
      float4 q = *(const float4*)(ap + kk*32 + g*4 + 16);
      U8 u;
      u.s[0]=f2b(p.x); u.s[1]=f2b(p.y); u.s[2]=f2b(p.z); u.s[3]=f2b(p.w);
      u.s[4]=f2b(q.x); u.s[5]=f2b(q.y); u.s[6]=f2b(q.z); u.s[7]=f2b(q.w);
      a[kk] = u.b;
    }
  } else {
    const u16* ap = (const u16*)A + (size_t)(tile*16 + mr)*128;
    #pragma unroll
    for (int kk = 0; kk < 4; ++kk){
      U8 u;
      u.q[0] = *(const ushort4*)(ap + kk*32 + g*4);
      u.q[1] = *(const ushort4*)(ap + kk*32 + g*4 + 16);
      a[kk] = u.b;
    }
  }
  float dj[4];
  #pragma unroll
  for (int j = 0; j < 4; ++j) dj[j] = dis[tile*16 + g*4 + j];
  #pragma unroll
  for (int nt = 0; nt < 8; ++nt){
    f32x4 acc = {0.f,0.f,0.f,0.f};
    #pragma unroll
    for (int kk = 0; kk < 4; ++kk){
      bf16x8 b = *(const bf16x8*)(Ws + (size_t)((nt*4 + kk)*64 + lane)*8);
      acc = __builtin_amdgcn_mfma_f32_16x16x32_bf16(a[kk], b, acc, 0, 0, 0);
    }
    int nn = nt*16 + mr;
    #pragma unroll
    for (int j = 0; j < 4; ++j){
      int row = tile*16 + g*4 + j;
      T[(size_t)row*128 + nn] = f2b(acc[j] * dj[j]);
    }
  }
}

// aggregation + bias + epilogue. One wave per node, 4 nodes per block.
template<int MODE>
__global__ __launch_bounds__(256) void k_agg(const u16* __restrict__ T,
    const int* __restrict__ rowptr, const int* __restrict__ colx,
    const float* __restrict__ dis, const void* __restrict__ bias,
    const void* __restrict__ lg, const void* __restrict__ lb,
    void* __restrict__ outA, int n, const int* __restrict__ flags)
{
  int wave = threadIdx.x >> 6, l = threadIdx.x & 63;
  int v = blockIdx.x*4 + wave; if (v >= n) return;
  int f = flags[0];
  int d0 = l*2;
  u32 self = *(const u32*)(T + (size_t)v*128 + d0);
  float p0 = b2f((u16)(self & 0xffff)), p1 = b2f((u16)(self >> 16));
  float q0 = 0.f, q1 = 0.f, r0 = 0.f, r1 = 0.f, t0 = 0.f, t1 = 0.f;
  int s = rowptr[v], e = rowptr[v+1];
  for (int base = s; base < e; base += 64){
    int cnt = e - base; if (cnt > 64) cnt = 64;
    int my = (base + l < e) ? colx[base + l] : 0;
    int i = 0;
    for (; i + 4 <= cnt; i += 4){
      int nb0 = __shfl(my, i), nb1 = __shfl(my, i+1);
      int nb2 = __shfl(my, i+2), nb3 = __shfl(my, i+3);
      u32 u0 = *(const u32*)(T + (size_t)nb0*128 + d0);
      u32 u1 = *(const u32*)(T + (size_t)nb1*128 + d0);
      u32 u2 = *(const u32*)(T + (size_t)nb2*128 + d0);
      u32 u3 = *(const u32*)(T + (size_t)nb3*128 + d0);
      p0 += b2f((u16)(u0 & 0xffff)); p1 += b2f((u16)(u0 >> 16));
      q0 += b2f((u16)(u1 & 0xffff)); q1 += b2f((u16)(u1 >> 16));
      r0 += b2f((u16)(u2 & 0xffff)); r1 += b2f((u16)(u2 >> 16));
      t0 += b2f((u16)(u3 & 0xffff)); t1 += b2f((u16)(u3 >> 16));
    }
    for (; i < cnt; ++i){
      int nb = __shfl(my, i);
      u32 u = *(const u32*)(T + (size_t)nb*128 + d0);
      p0 += b2f((u16)(u & 0xffff)); p1 += b2f((u16)(u >> 16));
    }
  }
  float a0 = (p0 + q0) + (r0 + t0);
  float a1 = (p1 + q1) + (r1 + t1);
  float sc = dis[v];
  float x0 = fmaf(a0, sc, ld_f(bias, d0,   f));
  float x1 = fmaf(a1, sc, ld_f(bias, d0+1, f));
  if (MODE == 0){
    x0 = fmaxf(x0, 0.f); x1 = fmaxf(x1, 0.f);
    float sum = x0 + x1;
    #pragma unroll
    for (int off = 32; off; off >>= 1) sum += __shfl_xor(sum, off);
    float mu = sum * (1.f/128.f);
    float e0 = x0 - mu, e1 = x1 - mu;
    float vs = e0*e0 + e1*e1;
    #pragma unroll
    for (int off = 32; off; off >>= 1) vs += __shfl_xor(vs, off);
    float inv = rsqrtf(vs*(1.f/128.f) + 1e-5f);
    u16* oa = (u16*)outA;
    oa[(size_t)v*128 + d0]   = f2b(e0*inv*ld_f(lg, d0,   f) + ld_f(lb, d0,   f));
    oa[(size_t)v*128 + d0+1] = f2b(e1*inv*ld_f(lg, d0+1, f) + ld_f(lb, d0+1, f));
  } else {
    if (f){
      float* oa = (float*)outA;
      oa[(size_t)v*128 + d0]   = x0;
      oa[(size_t)v*128 + d0+1] = x1;
    } else {
      u16* oa = (u16*)outA;
      oa[(size_t)v*128 + d0]   = f2b(x0);
      oa[(size_t)v*128 + d0+1] = f2b(x1);
    }
  }
}

// collapse post_mp: Wc = mpW1 @ mpW2 (128x40 f32), bc = mpb1 @ mpW2 + mpb2
__global__ __launch_bounds__(128) void k_wc(const void* __restrict__ mpW1, const void* __restrict__ mpb1,
    const void* __restrict__ mpW2, const void* __restrict__ mpb2,
    float* __restrict__ Wc, float* __restrict__ bc, const int* __restrict__ flags)
{
  int f = flags[0];
  int c = blockIdx.x;   // 0..39
  int k = threadIdx.x;  // 0..127
  float acc = 0.f;
  if (f){
    const float* A  = (const float*)mpW1 + (size_t)k*128;
    const float* B2 = (const float*)mpW2;
    #pragma unroll 8
    for (int j = 0; j < 128; ++j) acc = fmaf(A[j], B2[j*40 + c], acc);
    if (k == 0){
      const float* b1p = (const float*)mpb1;
      float b = ((const float*)mpb2)[c];
      #pragma unroll 8
      for (int j = 0; j < 128; ++j) b = fmaf(b1p[j], B2[j*40 + c], b);
      bc[c] = b;
    }
  } else {
    const u16* A  = (const u16*)mpW1 + (size_t)k*128;
    const u16* B2 = (const u16*)mpW2;
    #pragma unroll 8
    for (int j = 0; j < 128; ++j) acc = fmaf(b2f(A[j]), b2f(B2[j*40 + c]), acc);
    if (k == 0){
      const u16* b1p = (const u16*)mpb1;
      float b = b2f(((const u16*)mpb2)[c]);
      #pragma unroll 8
      for (int j = 0; j < 128; ++j) b = fmaf(b2f(b1p[j]), b2f(B2[j*40 + c]), b);
      bc[c] = b;
    }
  }
  Wc[k*40 + c] = acc;
}

// shuffle Wc (128x40 f32) -> bf16 B-frags padded to 48 cols. 12 frags.
__global__ __launch_bounds__(64) void k_shufWc(const float* __restrict__ Wc, u16* __restrict__ Wcs){
  int bid = blockIdx.x;          // 0..11
  int nt = bid >> 2, kk = bid & 3;
  int l = threadIdx.x;
  int g = l >> 4, mr = l & 15;
  int nn = nt*16 + mr;
  #pragma unroll
  for (int i = 0; i < 8; ++i){
    int k = kk*32 + g*4 + (i & 3) + ((i >> 2) << 4);
    Wcs[(size_t)(bid*64 + l)*8 + i] = (nn < 40) ? f2b(Wc[k*40 + nn]) : (u16)0;
  }
}

// logits via MFMA + in-register log_softmax. One wave per 16-node tile.
__global__ __launch_bounds__(256) void k_logitsM(const u16* __restrict__ Wcs,
    const float* __restrict__ bc, void* __restrict__ dout, int n,
    const int* __restrict__ flags)
{
  int wave = threadIdx.x >> 6, lane = threadIdx.x & 63;
  int tile = blockIdx.x*4 + wave;
  int nTiles = n >> 4;
  if (tile >= nTiles) return;
  int f = flags[0];
  int g = lane >> 4, mr = lane & 15;
  union U8 { ushort4 q[2]; u16 s[8]; bf16x8 b; };
  bf16x8 a[4];
  if (f){
    const float* ap = (const float*)dout + (size_t)(tile*16 + mr)*128;
    #pragma unroll
    for (int kk = 0; kk < 4; ++kk){
      float4 p = *(const float4*)(ap + kk*32 + g*4);
      float4 q = *(const float4*)(ap + kk*32 + g*4 + 16);
      U8 u;
      u.s[0]=f2b(fmaxf(p.x,0.f)); u.s[1]=f2b(fmaxf(p.y,0.f));
      u.s[2]=f2b(fmaxf(p.z,0.f)); u.s[3]=f2b(fmaxf(p.w,0.f));
      u.s[4]=f2b(fmaxf(q.x,0.f)); u.s[5]=f2b(fmaxf(q.y,0.f));
      u.s[6]=f2b(fmaxf(q.z,0.f)); u.s[7]=f2b(fmaxf(q.w,0.f));
      a[kk] = u.b;
    }
  } else {
    const u16* ap = (const u16*)dout + (size_t)(tile*16 + mr)*128;
    #pragma unroll
    for (int kk = 0; kk < 4; ++kk){
      U8 u;
      u.q[0] = *(const ushort4*)(ap + kk*32 + g*4);
      u.q[1] = *(const ushort4*)(ap + kk*32 + g*4 + 16);
      #pragma unroll
      for (int i = 0; i < 8; ++i) u.s[i] = (u.s[i] & 0x8000u) ? (u16)0 : u.s[i];  // relu
      a[kk] = u.b;
    }
  }
  f32x4 acc[3];
  #pragma unroll
  for (int nt = 0; nt < 3; ++nt){
    f32x4 c4 = {0.f,0.f,0.f,0.f};
    #pragma unroll
    for (int kk = 0; kk < 4; ++kk){
      bf16x8 b = *(const bf16x8*)(Wcs + (size_t)((nt*4 + kk)*64 + lane)*8);
      c4 = __builtin_amdgcn_mfma_f32_16x16x32_bf16(a[kk], b, c4, 0, 0, 0);
    }
    acc[nt] = c4;
  }
  float bcv[3]; bool valid[3];
  #pragma unroll
  for (int nt = 0; nt < 3; ++nt){
    int c = nt*16 + mr;
    valid[nt] = (c < 40);
    bcv[nt] = valid[nt] ? bc[c] : 0.f;
  }
  float* of = (float*)dout + (size_t)n*128;
  u16*  ob = (u16*) dout + (size_t)n*128;
  #pragma unroll
  for (int j = 0; j < 4; ++j){
    float l0 = valid[0] ? acc[0][j] + bcv[0] : -3.0e38f;
    float l1 = valid[1] ? acc[1][j] + bcv[1] : -3.0e38f;
    float l2 = valid[2] ? acc[2][j] + bcv[2] : -3.0e38f;
    float m = fmaxf(l0, fmaxf(l1, l2));
    #pragma unroll
    for (int off = 8; off; off >>= 1) m = fmaxf(m, __shfl_xor(m, off));
    float ssum = (valid[0] ? expf(l0 - m) : 0.f)
               + (valid[1] ? expf(l1 - m) : 0.f)
               + (valid[2] ? expf(l2 - m) : 0.f);
    #pragma unroll
    for (int off = 8; off; off >>= 1) ssum += __shfl_xor(ssum, off);
    float lgs = m + logf(ssum);
    int node = tile*16 + g*4 + j;
    #pragma unroll
    for (int nt = 0; nt < 3; ++nt){
      if (valid[nt]){
        int c = nt*16 + mr;
        float r = (nt==0 ? l0 : (nt==1 ? l1 : l2)) - lgs;
        if (f) of[(size_t)node*40 + c] = r;
        else   ob[(size_t)node*40 + c] = f2b(r);
      }
    }
  }
}

extern "C" void kernel_launch(void* const* d_in, const int* in_sizes, int n_in,
                              void* d_out, int out_size, void* d_ws, size_t ws_size,
                              hipStream_t stream)
{
  const int n = in_sizes[0] / 128;
  const int E = in_sizes[1] / 2;

  const void* x    = d_in[0];
  const void* ei   = d_in[1];
  const void* W1   = d_in[2];
  const void* b1   = d_in[3];
  const void* W2   = d_in[4];
  const void* b2   = d_in[5];
  const void* W3   = d_in[6];
  const void* b3   = d_in[7];
  const void* ln1g = d_in[8];
  const void* ln1b = d_in[9];
  const void* ln2g = d_in[10];
  const void* ln2b = d_in[11];
  const void* mpW1 = d_in[12];
  const void* mpb1 = d_in[13];
  const void* mpW2 = d_in[14];
  const void* mpb2 = d_in[15];

  u16* Hbuf = (u16*)d_out;  // d_out emb region doubles as H buffer until layer 3

  char* w = (char*)d_ws;
  size_t off = 0;
  auto alloc = [&](size_t bytes)->char*{
    char* p = w + off; off = (off + bytes + 255) & ~(size_t)255; return p;
  };
  const int nbuk = (n + (1<<BSH) - 1) >> BSH;

  int*   flags = (int*)  alloc(256);
  float* dis   = (float*)alloc((size_t)n*4);
  int*   deg   = (int*)  alloc((size_t)n*4);
  int*   rowp  = (int*)  alloc((size_t)(n+1)*4);
  int*   bsum  = (int*)  alloc(1024);
  int*   bcnt  = (int*)  alloc((size_t)nbuk*4);
  u32*   ebuf  = (u32*)  alloc((size_t)nbuk*BCAP*4);
  int*   colx  = (int*)  alloc((size_t)E*4 + 256);
  u16*   T     = (u16*)  alloc((size_t)n*128*2);
  u16*   Ws    = (u16*)  alloc((size_t)128*128*2);
  float* Wc    = (float*)alloc((size_t)128*40*4);
  float* bc    = (float*)alloc((size_t)64*4);
  u16*   Wcs   = (u16*)  alloc((size_t)12*64*8*2);

  int nB = (n + 1023) / 1024;

  k_detect<<<1, 256, 0, stream>>>((const u16*)x, (const u32*)ei, flags);
  k_zerob <<<(nbuk + 255)/256, 256, 0, stream>>>(bcnt, nbuk);
  k_part  <<<NPB, 256, 0, stream>>>(ei, E, n, bcnt, ebuf, flags, nbuk);
  k_bdeg  <<<nbuk, 256, 0, stream>>>(bcnt, ebuf, deg, n);
  k_scanA <<<nB, 256, 0, stream>>>(deg, n, bsum);
  k_scanB <<<1, 256, 0, stream>>>(bsum, nB, rowp, n);
  k_scanC <<<nB, 256, 0, stream>>>(deg, n, bsum, rowp, dis);
  k_bfill <<<nbuk, 256, 0, stream>>>(bcnt, ebuf, rowp, colx, n);
  k_wc    <<<40, 128, 0, stream>>>(mpW1, mpb1, mpW2, mpb2, Wc, bc, flags);
  k_shufWc<<<12, 64, 0, stream>>>(Wc, Wcs);

  int nTiles = (n + 15) / 16;
  int gG = (nTiles + 3) / 4;
  int gA = (n + 3) / 4;

  // layer 0
  k_shufW<<<32, 64, 0, stream>>>(W1, Ws, flags);
  k_gemm <<<gG, 256, 0, stream>>>(x, 1, Ws, dis, T, nTiles, flags);
  k_agg<0><<<gA, 256, 0, stream>>>(T, rowp, colx, dis, b1, ln1g, ln1b, Hbuf, n, flags);
  // layer 1
  k_shufW<<<32, 64, 0, stream>>>(W2, Ws, flags);
  k_gemm <<<gG, 256, 0, stream>>>(Hbuf, 0, Ws, dis, T, nTiles, flags);
  k_agg<0><<<gA, 256, 0, stream>>>(T, rowp, colx, dis, b2, ln2g, ln2b, Hbuf, n, flags);
  // layer 2: emb -> d_out
  k_shufW<<<32, 64, 0, stream>>>(W3, Ws, flags);
  k_gemm <<<gG, 256, 0, stream>>>(Hbuf, 0, Ws, dis, T, nTiles, flags);
  k_agg<1><<<gA, 256, 0, stream>>>(T, rowp, colx, dis, b3, nullptr, nullptr, d_out, n, flags);
  // post_mp collapsed + log_softmax (MFMA)
  k_logitsM<<<gG, 256, 0, stream>>>(Wcs, bc, d_out, n, flags);
}

// Round 7
// 237.058 us; speedup vs baseline: 2.1367x; 1.1123x over previous
//
#include <hip/hip_runtime.h>

typedef __bf16 bf16x8 __attribute__((ext_vector_type(8)));
typedef float  f32x4  __attribute__((ext_vector_type(4)));
typedef unsigned short u16;
typedef unsigned int   u32;
typedef long long      i64;

#define BSH  7                    // nodes per bucket = 128
#define BCAP 4096                 // max edges per bucket (mean ~2045)
#define NPB  256                  // partition blocks (== threads in scan)

__device__ __forceinline__ float b2f(u16 x){ return __uint_as_float(((u32)x) << 16); }
__device__ __forceinline__ u16 f2b(float x){
  u32 u = __float_as_uint(x);
  return (u16)((u + 0x7FFFu + ((u >> 16) & 1u)) >> 16);
}

// flags[0] = 1 if float tensors are f32 on device (else bf16)
// flags[1] = 1 if edge_index is int64 on device (else int32)
__global__ __launch_bounds__(256) void k_detect(const u16* __restrict__ x,
                                                const u32* __restrict__ ei,
                                                int* __restrict__ flags){
  __shared__ int sh[2];
  int t = threadIdx.x;
  if (t < 2) sh[t] = 0;
  __syncthreads();
  int sane = 0;
  for (int i = t; i < 4096; i += 256){
    u16 u = x[i]; u32 e = (u >> 7) & 0xFFu;
    if (u == 0 || (e >= 0x70u && e <= 0x8Fu)) sane++;
  }
  int nz = 0;
  for (int i = t; i < 1024; i += 256)
    if (ei[2*i + 1] != 0u) nz++;
  atomicAdd(&sh[0], sane);
  atomicAdd(&sh[1], nz);
  __syncthreads();
  if (t == 0){
    flags[0] = (sh[0] < 3500) ? 1 : 0;
    flags[1] = (sh[1] == 0) ? 1 : 0;
  }
}

__device__ __forceinline__ int ld_idx(const void* ei, long long j, int is64){
  return is64 ? (int)((const i64*)ei)[j] : ((const int*)ei)[j];
}
__device__ __forceinline__ float ld_f(const void* p, int j, int isf32){
  return isf32 ? ((const float*)p)[j] : b2f(((const u16*)p)[j]);
}

// ---- atomic-free 3-phase edge partition ----
// A) per-block LDS histogram -> cntmat[bucket][block]
__global__ __launch_bounds__(256) void k_partA(const void* __restrict__ ei, int E, int n,
                                               int* __restrict__ cntmat,
                                               const int* __restrict__ flags, int nbuk){
  __shared__ int cnt[512];
  int t = threadIdx.x;
  int is64 = flags[1];
  for (int i = t; i < 512; i += 256) cnt[i] = 0;
  __syncthreads();
  long long R = ((long long)E + NPB - 1) / NPB;
  long long lo = (long long)blockIdx.x * R;
  long long hi = lo + R; if (hi > E) hi = E;
  for (long long e = lo + t; e < hi; e += 256){
    int d = ld_idx(ei, (long long)E + e, is64);
    if ((unsigned)d < (unsigned)n) atomicAdd(&cnt[(unsigned)d >> BSH], 1);
  }
  __syncthreads();
  for (int b = t; b < nbuk; b += 256)
    cntmat[(size_t)b*NPB + blockIdx.x] = cnt[b];
}

// B) per-bucket exclusive scan over blocks -> basemat, bcnt
__global__ __launch_bounds__(NPB) void k_scanBK(const int* __restrict__ cntmat,
                                                int* __restrict__ basemat,
                                                int* __restrict__ bcnt){
  __shared__ int sh[NPB];
  int b = blockIdx.x, t = threadIdx.x;
  int v = cntmat[(size_t)b*NPB + t];
  sh[t] = v; __syncthreads();
  for (int off = 1; off < NPB; off <<= 1){
    int u = 0; if (t >= off) u = sh[t - off];
    __syncthreads(); sh[t] += u; __syncthreads();
  }
  basemat[(size_t)b*NPB + t] = sh[t] - v;
  if (t == NPB-1) bcnt[b] = sh[t];
}

// C) scatter via LDS cursors into reserved ranges (no global atomics)
__global__ __launch_bounds__(256) void k_partC(const void* __restrict__ ei, int E, int n,
                                               const int* __restrict__ basemat,
                                               u32* __restrict__ ebuf,
                                               const int* __restrict__ flags, int nbuk){
  __shared__ int cur[512];
  int t = threadIdx.x;
  int is64 = flags[1];
  for (int i = t; i < 512; i += 256) cur[i] = 0;
  __syncthreads();
  for (int b = t; b < nbuk; b += 256) cur[b] = basemat[(size_t)b*NPB + blockIdx.x];
  __syncthreads();
  long long R = ((long long)E + NPB - 1) / NPB;
  long long lo = (long long)blockIdx.x * R;
  long long hi = lo + R; if (hi > E) hi = E;
  for (long long e = lo + t; e < hi; e += 256){
    int d = ld_idx(ei, (long long)E + e, is64);
    int s = ld_idx(ei, e, is64);
    if ((unsigned)d < (unsigned)n && (unsigned)s < (unsigned)n){
      int b = (unsigned)d >> BSH;
      int p = atomicAdd(&cur[b], 1);
      if (p < BCAP) ebuf[(size_t)b*BCAP + p] = (u32)s | ((u32)(d & ((1<<BSH)-1)) << 17);
    }
  }
}

// per-bucket LDS histogram -> deg
__global__ __launch_bounds__(256) void k_bdeg(const int* __restrict__ bcnt,
                                              const u32* __restrict__ ebuf,
                                              int* __restrict__ deg, int n){
  __shared__ int cnt[1<<BSH];
  int b = blockIdx.x, t = threadIdx.x;
  if (t < (1<<BSH)) cnt[t] = 0;
  __syncthreads();
  int m = bcnt[b]; if (m > BCAP) m = BCAP;
  const u32* eb = ebuf + (size_t)b*BCAP;
  for (int i = t; i < m; i += 256)
    atomicAdd(&cnt[eb[i] >> 17], 1);
  __syncthreads();
  if (t < (1<<BSH)){
    int node = (b << BSH) + t;
    if (node < n) deg[node] = cnt[t];
  }
}

// ---- hierarchical scan over node degrees ----
__global__ __launch_bounds__(256) void k_scanA(const int* __restrict__ deg, int n,
                                               int* __restrict__ bsum){
  __shared__ int sh[256];
  int t = threadIdx.x;
  int base = blockIdx.x*1024 + t*4;
  int s = 0;
  #pragma unroll
  for (int i = 0; i < 4; ++i){ int idx = base + i; if (idx < n) s += deg[idx]; }
  sh[t] = s; __syncthreads();
  for (int off = 128; off; off >>= 1){
    if (t < off) sh[t] += sh[t + off];
    __syncthreads();
  }
  if (t == 0) bsum[blockIdx.x] = sh[0];
}

__global__ __launch_bounds__(256) void k_scanB(int* __restrict__ bsum, int nB,
                                               int* __restrict__ rowptr, int n){
  __shared__ int sh[256];
  int t = threadIdx.x;
  int v = (t < nB) ? bsum[t] : 0;
  sh[t] = v; __syncthreads();
  for (int off = 1; off < 256; off <<= 1){
    int u = 0; if (t >= off) u = sh[t - off];
    __syncthreads(); sh[t] += u; __syncthreads();
  }
  if (t < nB) bsum[t] = sh[t] - v;
  if (t == 255) rowptr[n] = sh[255];
}

__global__ __launch_bounds__(256) void k_scanC(const int* __restrict__ deg, int n,
                                               const int* __restrict__ bsum,
                                               int* __restrict__ rowptr,
                                               float* __restrict__ dis){
  __shared__ int sh[256];
  int t = threadIdx.x;
  int base = blockIdx.x*1024 + t*4;
  int d[4]; int s = 0;
  #pragma unroll
  for (int i = 0; i < 4; ++i){ int idx = base + i; d[i] = (idx < n) ? deg[idx] : 0; s += d[i]; }
  sh[t] = s; __syncthreads();
  for (int off = 1; off < 256; off <<= 1){
    int u = 0; if (t >= off) u = sh[t - off];
    __syncthreads(); sh[t] += u; __syncthreads();
  }
  int run = bsum[blockIdx.x] + sh[t] - s;
  #pragma unroll
  for (int i = 0; i < 4; ++i){
    int idx = base + i;
    if (idx < n){
      rowptr[idx] = run; run += d[i];
      dis[idx] = rsqrtf((float)(d[i] + 1));
    }
  }
}

// per-bucket CSR fill with LDS cursors (colx window is L2-local)
__global__ __launch_bounds__(256) void k_bfill(const int* __restrict__ bcnt,
                                               const u32* __restrict__ ebuf,
                                               const int* __restrict__ rowptr,
                                               int* __restrict__ colx, int n){
  __shared__ int cur[1<<BSH];
  int b = blockIdx.x, t = threadIdx.x;
  if (t < (1<<BSH)){
    int node = (b << BSH) + t;
    cur[t] = (node < n) ? rowptr[node] : 0;
  }
  __syncthreads();
  int m = bcnt[b]; if (m > BCAP) m = BCAP;
  const u32* eb = ebuf + (size_t)b*BCAP;
  for (int i = t; i < m; i += 256){
    u32 e = eb[i];
    int p = atomicAdd(&cur[e >> 17], 1);
    colx[p] = (int)(e & 0x1FFFFu);
  }
}

// pre-shuffle W (128x128) into MFMA B-fragment order (bf16 out)
__global__ __launch_bounds__(64) void k_shufW(const void* __restrict__ W, u16* __restrict__ Ws,
                                              const int* __restrict__ flags){
  int f = flags[0];
  int bid = blockIdx.x;          // 0..31
  int nt = bid >> 2, kk = bid & 3;
  int l = threadIdx.x;
  int g = l >> 4, mr = l & 15;
  int nn = nt*16 + mr;
  #pragma unroll
  for (int i = 0; i < 8; ++i){
    int k = kk*32 + g*4 + (i & 3) + ((i >> 2) << 4);
    u16 w = f ? f2b(((const float*)W)[k*128 + nn]) : ((const u16*)W)[k*128 + nn];
    Ws[(size_t)(bid*64 + l)*8 + i] = w;
  }
}

// T = (A @ W) * dis[row], bf16 out. One wave per 16-row tile.
__global__ __launch_bounds__(256) void k_gemm(const void* __restrict__ A, int aExt,
    const u16* __restrict__ Ws, const float* __restrict__ dis,
    u16* __restrict__ T, int nTiles, const int* __restrict__ flags)
{
  int wave = threadIdx.x >> 6, lane = threadIdx.x & 63;
  int tile = blockIdx.x*4 + wave;
  if (tile >= nTiles) return;
  int g = lane >> 4, mr = lane & 15;
  int f = aExt ? flags[0] : 0;
  union U8 { ushort4 q[2]; u16 s[8]; bf16x8 b; };
  bf16x8 a[4];
  if (f){
    const float* ap = (const float*)A + (size_t)(tile*16 + mr)*128;
    #pragma unroll
    for (int kk = 0; kk < 4; ++kk){
      float4 p = *(const float4*)(ap + kk*32 + g*4);
      float4 q = *(const float4*)(ap + kk*32 + g*4 + 16);
      U8 u;
      u.s[0]=f2b(p.x); u.s[1]=f2b(p.y); u.s[2]=f2b(p.z); u.s[3]=f2b(p.w);
      u.s[4]=f2b(q.x); u.s[5]=f2b(q.y); u.s[6]=f2b(q.z); u.s[7]=f2b(q.w);
      a[kk] = u.b;
    }
  } else {
    const u16* ap = (const u16*)A + (size_t)(tile*16 + mr)*128;
    #pragma unroll
    for (int kk = 0; kk < 4; ++kk){
      U8 u;
      u.q[0] = *(const ushort4*)(ap + kk*32 + g*4);
      u.q[1] = *(const ushort4*)(ap + kk*32 + g*4 + 16);
      a[kk] = u.b;
    }
  }
  float dj[4];
  #pragma unroll
  for (int j = 0; j < 4; ++j) dj[j] = dis[tile*16 + g*4 + j];
  #pragma unroll
  for (int nt = 0; nt < 8; ++nt){
    f32x4 acc = {0.f,0.f,0.f,0.f};
    #pragma unroll
    for (int kk = 0; kk < 4; ++kk){
      bf16x8 b = *(const bf16x8*)(Ws + (size_t)((nt*4 + kk)*64 + lane)*8);
      acc = __builtin_amdgcn_mfma_f32_16x16x32_bf16(a[kk], b, acc, 0, 0, 0);
    }
    int nn = nt*16 + mr;
    #pragma unroll
    for (int j = 0; j < 4; ++j){
      int row = tile*16 + g*4 + j;
      T[(size_t)row*128 + nn] = f2b(acc[j] * dj[j]);
    }
  }
}

// aggregation + bias + epilogue. One wave per node, 4 nodes per block.
// 8 independent gathers in flight per iteration (L2/L3 latency-bound).
template<int MODE>
__global__ __launch_bounds__(256) void k_agg(const u16* __restrict__ T,
    const int* __restrict__ rowptr, const int* __restrict__ colx,
    const float* __restrict__ dis, const void* __restrict__ bias,
    const void* __restrict__ lg, const void* __restrict__ lb,
    void* __restrict__ outA, int n, const int* __restrict__ flags)
{
  int wave = threadIdx.x >> 6, l = threadIdx.x & 63;
  int v = blockIdx.x*4 + wave; if (v >= n) return;
  int f = flags[0];
  int d0 = l*2;
  u32 self = *(const u32*)(T + (size_t)v*128 + d0);
  float p0 = b2f((u16)(self & 0xffff)), p1 = b2f((u16)(self >> 16));
  float q0 = 0.f, q1 = 0.f, r0 = 0.f, r1 = 0.f, t0 = 0.f, t1 = 0.f;
  int s = rowptr[v], e = rowptr[v+1];
  for (int base = s; base < e; base += 64){
    int cnt = e - base; if (cnt > 64) cnt = 64;
    int my = (base + l < e) ? colx[base + l] : 0;
    int i = 0;
    for (; i + 8 <= cnt; i += 8){
      int nb0 = __shfl(my, i),   nb1 = __shfl(my, i+1);
      int nb2 = __shfl(my, i+2), nb3 = __shfl(my, i+3);
      int nb4 = __shfl(my, i+4), nb5 = __shfl(my, i+5);
      int nb6 = __shfl(my, i+6), nb7 = __shfl(my, i+7);
      u32 u0 = *(const u32*)(T + (size_t)nb0*128 + d0);
      u32 u1 = *(const u32*)(T + (size_t)nb1*128 + d0);
      u32 u2 = *(const u32*)(T + (size_t)nb2*128 + d0);
      u32 u3 = *(const u32*)(T + (size_t)nb3*128 + d0);
      u32 u4 = *(const u32*)(T + (size_t)nb4*128 + d0);
      u32 u5 = *(const u32*)(T + (size_t)nb5*128 + d0);
      u32 u6 = *(const u32*)(T + (size_t)nb6*128 + d0);
      u32 u7 = *(const u32*)(T + (size_t)nb7*128 + d0);
      p0 += b2f((u16)(u0 & 0xffff)) + b2f((u16)(u4 & 0xffff));
      p1 += b2f((u16)(u0 >> 16))    + b2f((u16)(u4 >> 16));
      q0 += b2f((u16)(u1 & 0xffff)) + b2f((u16)(u5 & 0xffff));
      q1 += b2f((u16)(u1 >> 16))    + b2f((u16)(u5 >> 16));
      r0 += b2f((u16)(u2 & 0xffff)) + b2f((u16)(u6 & 0xffff));
      r1 += b2f((u16)(u2 >> 16))    + b2f((u16)(u6 >> 16));
      t0 += b2f((u16)(u3 & 0xffff)) + b2f((u16)(u7 & 0xffff));
      t1 += b2f((u16)(u3 >> 16))    + b2f((u16)(u7 >> 16));
    }
    for (; i + 4 <= cnt; i += 4){
      int nb0 = __shfl(my, i), nb1 = __shfl(my, i+1);
      int nb2 = __shfl(my, i+2), nb3 = __shfl(my, i+3);
      u32 u0 = *(const u32*)(T + (size_t)nb0*128 + d0);
      u32 u1 = *(const u32*)(T + (size_t)nb1*128 + d0);
      u32 u2 = *(const u32*)(T + (size_t)nb2*128 + d0);
      u32 u3 = *(const u32*)(T + (size_t)nb3*128 + d0);
      p0 += b2f((u16)(u0 & 0xffff)); p1 += b2f((u16)(u0 >> 16));
      q0 += b2f((u16)(u1 & 0xffff)); q1 += b2f((u16)(u1 >> 16));
      r0 += b2f((u16)(u2 & 0xffff)); r1 += b2f((u16)(u2 >> 16));
      t0 += b2f((u16)(u3 & 0xffff)); t1 += b2f((u16)(u3 >> 16));
    }
    for (; i < cnt; ++i){
      int nb = __shfl(my, i);
      u32 u = *(const u32*)(T + (size_t)nb*128 + d0);
      p0 += b2f((u16)(u & 0xffff)); p1 += b2f((u16)(u >> 16));
    }
  }
  float a0 = (p0 + q0) + (r0 + t0);
  float a1 = (p1 + q1) + (r1 + t1);
  float sc = dis[v];
  float x0 = fmaf(a0, sc, ld_f(bias, d0,   f));
  float x1 = fmaf(a1, sc, ld_f(bias, d0+1, f));
  if (MODE == 0){
    x0 = fmaxf(x0, 0.f); x1 = fmaxf(x1, 0.f);
    float sum = x0 + x1;
    #pragma unroll
    for (int off = 32; off; off >>= 1) sum += __shfl_xor(sum, off);
    float mu = sum * (1.f/128.f);
    float e0 = x0 - mu, e1 = x1 - mu;
    float vs = e0*e0 + e1*e1;
    #pragma unroll
    for (int off = 32; off; off >>= 1) vs += __shfl_xor(vs, off);
    float inv = rsqrtf(vs*(1.f/128.f) + 1e-5f);
    u16* oa = (u16*)outA;
    oa[(size_t)v*128 + d0]   = f2b(e0*inv*ld_f(lg, d0,   f) + ld_f(lb, d0,   f));
    oa[(size_t)v*128 + d0+1] = f2b(e1*inv*ld_f(lg, d0+1, f) + ld_f(lb, d0+1, f));
  } else {
    if (f){
      float* oa = (float*)outA;
      oa[(size_t)v*128 + d0]   = x0;
      oa[(size_t)v*128 + d0+1] = x1;
    } else {
      u16* oa = (u16*)outA;
      oa[(size_t)v*128 + d0]   = f2b(x0);
      oa[(size_t)v*128 + d0+1] = f2b(x1);
    }
  }
}

// collapse post_mp: Wc = mpW1 @ mpW2 (128x40 f32), bc = mpb1 @ mpW2 + mpb2
__global__ __launch_bounds__(128) void k_wc(const void* __restrict__ mpW1, const void* __restrict__ mpb1,
    const void* __restrict__ mpW2, const void* __restrict__ mpb2,
    float* __restrict__ Wc, float* __restrict__ bc, const int* __restrict__ flags)
{
  int f = flags[0];
  int c = blockIdx.x;   // 0..39
  int k = threadIdx.x;  // 0..127
  float acc = 0.f;
  if (f){
    const float* A  = (const float*)mpW1 + (size_t)k*128;
    const float* B2 = (const float*)mpW2;
    #pragma unroll 8
    for (int j = 0; j < 128; ++j) acc = fmaf(A[j], B2[j*40 + c], acc);
    if (k == 0){
      const float* b1p = (const float*)mpb1;
      float b = ((const float*)mpb2)[c];
      #pragma unroll 8
      for (int j = 0; j < 128; ++j) b = fmaf(b1p[j], B2[j*40 + c], b);
      bc[c] = b;
    }
  } else {
    const u16* A  = (const u16*)mpW1 + (size_t)k*128;
    const u16* B2 = (const u16*)mpW2;
    #pragma unroll 8
    for (int j = 0; j < 128; ++j) acc = fmaf(b2f(A[j]), b2f(B2[j*40 + c]), acc);
    if (k == 0){
      const u16* b1p = (const u16*)mpb1;
      float b = b2f(((const u16*)mpb2)[c]);
      #pragma unroll 8
      for (int j = 0; j < 128; ++j) b = fmaf(b2f(b1p[j]), b2f(B2[j*40 + c]), b);
      bc[c] = b;
    }
  }
  Wc[k*40 + c] = acc;
}

// shuffle Wc (128x40 f32) -> bf16 B-frags padded to 48 cols. 12 frags.
__global__ __launch_bounds__(64) void k_shufWc(const float* __restrict__ Wc, u16* __restrict__ Wcs){
  int bid = blockIdx.x;          // 0..11
  int nt = bid >> 2, kk = bid & 3;
  int l = threadIdx.x;
  int g = l >> 4, mr = l & 15;
  int nn = nt*16 + mr;
  #pragma unroll
  for (int i = 0; i < 8; ++i){
    int k = kk*32 + g*4 + (i & 3) + ((i >> 2) << 4);
    Wcs[(size_t)(bid*64 + l)*8 + i] = (nn < 40) ? f2b(Wc[k*40 + nn]) : (u16)0;
  }
}

// logits via MFMA + in-register log_softmax. One wave per 16-node tile.
__global__ __launch_bounds__(256) void k_logitsM(const u16* __restrict__ Wcs,
    const float* __restrict__ bc, void* __restrict__ dout, int n,
    const int* __restrict__ flags)
{
  int wave = threadIdx.x >> 6, lane = threadIdx.x & 63;
  int tile = blockIdx.x*4 + wave;
  int nTiles = n >> 4;
  if (tile >= nTiles) return;
  int f = flags[0];
  int g = lane >> 4, mr = lane & 15;
  union U8 { ushort4 q[2]; u16 s[8]; bf16x8 b; };
  bf16x8 a[4];
  if (f){
    const float* ap = (const float*)dout + (size_t)(tile*16 + mr)*128;
    #pragma unroll
    for (int kk = 0; kk < 4; ++kk){
      float4 p = *(const float4*)(ap + kk*32 + g*4);
      float4 q = *(const float4*)(ap + kk*32 + g*4 + 16);
      U8 u;
      u.s[0]=f2b(fmaxf(p.x,0.f)); u.s[1]=f2b(fmaxf(p.y,0.f));
      u.s[2]=f2b(fmaxf(p.z,0.f)); u.s[3]=f2b(fmaxf(p.w,0.f));
      u.s[4]=f2b(fmaxf(q.x,0.f)); u.s[5]=f2b(fmaxf(q.y,0.f));
      u.s[6]=f2b(fmaxf(q.z,0.f)); u.s[7]=f2b(fmaxf(q.w,0.f));
      a[kk] = u.b;
    }
  } else {
    const u16* ap = (const u16*)dout + (size_t)(tile*16 + mr)*128;
    #pragma unroll
    for (int kk = 0; kk < 4; ++kk){
      U8 u;
      u.q[0] = *(const ushort4*)(ap + kk*32 + g*4);
      u.q[1] = *(const ushort4*)(ap + kk*32 + g*4 + 16);
      #pragma unroll
      for (int i = 0; i < 8; ++i) u.s[i] = (u.s[i] & 0x8000u) ? (u16)0 : u.s[i];  // relu
      a[kk] = u.b;
    }
  }
  f32x4 acc[3];
  #pragma unroll
  for (int nt = 0; nt < 3; ++nt){
    f32x4 c4 = {0.f,0.f,0.f,0.f};
    #pragma unroll
    for (int kk = 0; kk < 4; ++kk){
      bf16x8 b = *(const bf16x8*)(Wcs + (size_t)((nt*4 + kk)*64 + lane)*8);
      c4 = __builtin_amdgcn_mfma_f32_16x16x32_bf16(a[kk], b, c4, 0, 0, 0);
    }
    acc[nt] = c4;
  }
  float bcv[3]; bool valid[3];
  #pragma unroll
  for (int nt = 0; nt < 3; ++nt){
    int c = nt*16 + mr;
    valid[nt] = (c < 40);
    bcv[nt] = valid[nt] ? bc[c] : 0.f;
  }
  float* of = (float*)dout + (size_t)n*128;
  u16*  ob = (u16*) dout + (size_t)n*128;
  #pragma unroll
  for (int j = 0; j < 4; ++j){
    float l0 = valid[0] ? acc[0][j] + bcv[0] : -3.0e38f;
    float l1 = valid[1] ? acc[1][j] + bcv[1] : -3.0e38f;
    float l2 = valid[2] ? acc[2][j] + bcv[2] : -3.0e38f;
    float m = fmaxf(l0, fmaxf(l1, l2));
    #pragma unroll
    for (int off = 8; off; off >>= 1) m = fmaxf(m, __shfl_xor(m, off));
    float ssum = (valid[0] ? expf(l0 - m) : 0.f)
               + (valid[1] ? expf(l1 - m) : 0.f)
               + (valid[2] ? expf(l2 - m) : 0.f);
    #pragma unroll
    for (int off = 8; off; off >>= 1) ssum += __shfl_xor(ssum, off);
    float lgs = m + logf(ssum);
    int node = tile*16 + g*4 + j;
    #pragma unroll
    for (int nt = 0; nt < 3; ++nt){
      if (valid[nt]){
        int c = nt*16 + mr;
        float r = (nt==0 ? l0 : (nt==1 ? l1 : l2)) - lgs;
        if (f) of[(size_t)node*40 + c] = r;
        else   ob[(size_t)node*40 + c] = f2b(r);
      }
    }
  }
}

extern "C" void kernel_launch(void* const* d_in, const int* in_sizes, int n_in,
                              void* d_out, int out_size, void* d_ws, size_t ws_size,
                              hipStream_t stream)
{
  const int n = in_sizes[0] / 128;
  const int E = in_sizes[1] / 2;

  const void* x    = d_in[0];
  const void* ei   = d_in[1];
  const void* W1   = d_in[2];
  const void* b1   = d_in[3];
  const void* W2   = d_in[4];
  const void* b2   = d_in[5];
  const void* W3   = d_in[6];
  const void* b3   = d_in[7];
  const void* ln1g = d_in[8];
  const void* ln1b = d_in[9];
  const void* ln2g = d_in[10];
  const void* ln2b = d_in[11];
  const void* mpW1 = d_in[12];
  const void* mpb1 = d_in[13];
  const void* mpW2 = d_in[14];
  const void* mpb2 = d_in[15];

  u16* Hbuf = (u16*)d_out;  // d_out emb region doubles as H buffer until layer 3

  char* w = (char*)d_ws;
  size_t off = 0;
  auto alloc = [&](size_t bytes)->char*{
    char* p = w + off; off = (off + bytes + 255) & ~(size_t)255; return p;
  };
  const int nbuk = (n + (1<<BSH) - 1) >> BSH;

  int*   flags = (int*)  alloc(256);
  float* dis   = (float*)alloc((size_t)n*4);
  int*   deg   = (int*)  alloc((size_t)n*4);
  int*   rowp  = (int*)  alloc((size_t)(n+1)*4);
  int*   bsum  = (int*)  alloc(1024);
  int*   bcnt  = (int*)  alloc((size_t)nbuk*4);
  int*   cntm  = (int*)  alloc((size_t)nbuk*NPB*4);
  int*   basem = (int*)  alloc((size_t)nbuk*NPB*4);
  u32*   ebuf  = (u32*)  alloc((size_t)nbuk*BCAP*4);
  int*   colx  = (int*)  alloc((size_t)E*4 + 256);
  u16*   T     = (u16*)  alloc((size_t)n*128*2);
  u16*   Ws    = (u16*)  alloc((size_t)128*128*2);
  float* Wc    = (float*)alloc((size_t)128*40*4);
  float* bc    = (float*)alloc((size_t)64*4);
  u16*   Wcs   = (u16*)  alloc((size_t)12*64*8*2);

  int nB = (n + 1023) / 1024;

  k_detect<<<1, 256, 0, stream>>>((const u16*)x, (const u32*)ei, flags);
  k_partA <<<NPB, 256, 0, stream>>>(ei, E, n, cntm, flags, nbuk);
  k_scanBK<<<nbuk, NPB, 0, stream>>>(cntm, basem, bcnt);
  k_partC <<<NPB, 256, 0, stream>>>(ei, E, n, basem, ebuf, flags, nbuk);
  k_bdeg  <<<nbuk, 256, 0, stream>>>(bcnt, ebuf, deg, n);
  k_scanA <<<nB, 256, 0, stream>>>(deg, n, bsum);
  k_scanB <<<1, 256, 0, stream>>>(bsum, nB, rowp, n);
  k_scanC <<<nB, 256, 0, stream>>>(deg, n, bsum, rowp, dis);
  k_bfill <<<nbuk, 256, 0, stream>>>(bcnt, ebuf, rowp, colx, n);
  k_wc    <<<40, 128, 0, stream>>>(mpW1, mpb1, mpW2, mpb2, Wc, bc, flags);
  k_shufWc<<<12, 64, 0, stream>>>(Wc, Wcs);

  int nTiles = (n + 15) / 16;
  int gG = (nTiles + 3) / 4;
  int gA = (n + 3) / 4;

  // layer 0
  k_shufW<<<32, 64, 0, stream>>>(W1, Ws, flags);
  k_gemm <<<gG, 256, 0, stream>>>(x, 1, Ws, dis, T, nTiles, flags);
  k_agg<0><<<gA, 256, 0, stream>>>(T, rowp, colx, dis, b1, ln1g, ln1b, Hbuf, n, flags);
  // layer 1
  k_shufW<<<32, 64, 0, stream>>>(W2, Ws, flags);
  k_gemm <<<gG, 256, 0, stream>>>(Hbuf, 0, Ws, dis, T, nTiles, flags);
  k_agg<0><<<gA, 256, 0, stream>>>(T, rowp, colx, dis, b2, ln2g, ln2b, Hbuf, n, flags);
  // layer 2: emb -> d_out
  k_shufW<<<32, 64, 0, stream>>>(W3, Ws, flags);
  k_gemm <<<gG, 256, 0, stream>>>(Hbuf, 0, Ws, dis, T, nTiles, flags);
  k_agg<1><<<gA, 256, 0, stream>>>(T, rowp, colx, dis, b3, nullptr, nullptr, d_out, n, flags);
  // post_mp collapsed + log_softmax (MFMA)
  k_logitsM<<<gG, 256, 0, stream>>>(Wcs, bc, d_out, n, flags);
}